// Round 12
// baseline (273.250 us; speedup 1.0000x reference)
//
#include <hip/hip_runtime.h>
#include <math.h>

#define D_   512
#define LAT_ 768
#define B_   16
#define S_   256
#define H_   8
#define DH_  64

typedef __bf16 bf16x8 __attribute__((ext_vector_type(8)));
typedef float f32x4 __attribute__((ext_vector_type(4)));

__device__ __forceinline__ unsigned short f2bf(float f) {
  unsigned u = __float_as_uint(f);
  unsigned r = (u + 0x7fffu + ((u >> 16) & 1u)) >> 16;
  return (unsigned short)r;
}

// ---------------- fused prep: mask canonicalization + segment starts ---------
__global__ void prep_k(const void* __restrict__ mask, int* __restrict__ maskc,
                       const int* __restrict__ gb, int* __restrict__ starts, int n) {
  int i = blockIdx.x * blockDim.x + threadIdx.x;
  if (i < B_ * S_) {
    const unsigned char* pb = (const unsigned char*)mask;
    const int*   pi = (const int*)mask;
    const float* pf = (const float*)mask;
    unsigned int w = ((const unsigned int*)mask)[1023];
    int v;
    if (w == 0x01010101u)      v = pb[i];
    else if (w == 0x3f800000u) v = (pf[i] != 0.0f);
    else                       v = (pi[i] != 0);
    maskc[i] = v ? 1 : 0;
  }
  if (i < n) {
    if (i == 0 || gb[i] != gb[i - 1]) starts[gb[i]] = i;
  }
}

// ---------------- scatter ragged nodes -> dense [B,Lmax,D] -------------------
__global__ __launch_bounds__(256) void scatter_k(const float* __restrict__ nodes,
    const int* __restrict__ gb, const int* __restrict__ starts,
    float* __restrict__ dense, int Lmax) {
  int i = blockIdx.x;
  int b = gb[i], p = i - starts[b];
  const float* src = nodes + (size_t)i * D_;
  float* dst = dense + ((size_t)b * Lmax + p) * D_;
  dst[threadIdx.x]       = src[threadIdx.x];
  dst[threadIdx.x + 256] = src[threadIdx.x + 256];
}

// ---------------- pack one (kc,n) chunk of B into MFMA layout ----------------
__device__ __forceinline__ void pack_chunk(const float* __restrict__ W,
    unsigned short* __restrict__ out, int K, int ntoff, int idx) {
  int n = idx & 511, kc = idx >> 9;
  int kt = kc >> 2, kblk = kc & 3;
  int nt = n >> 7, nblk = (n >> 4) & 7, col = n & 15;
  int KT = K >> 5;
  size_t ob = ((size_t)((nt + ntoff) * KT + kt) * 4096) + nblk * 512 + kblk * 128 + col * 8;
  unsigned short v[8];
#pragma unroll
  for (int j = 0; j < 8; ++j) v[j] = f2bf(W[(size_t)(kc * 8 + j) * 512 + n]);
  int4 pk;
  pk.x = v[0] | (v[1] << 16); pk.y = v[2] | (v[3] << 16);
  pk.z = v[4] | (v[5] << 16); pk.w = v[6] | (v[7] << 16);
  *(int4*)&out[ob] = pk;
}

__global__ __launch_bounds__(256) void pack1_k(const float* __restrict__ in_w,
    const float* __restrict__ Wo, const float* __restrict__ W1,
    unsigned short* iw0, unsigned short* iw1, unsigned short* iw2,
    unsigned short* Wo_pk, unsigned short* W1_pk) {
  int bid = blockIdx.x, sel = bid >> 7, within = bid & 127;
  const float* W; unsigned short* out;
  switch (sel) {
    case 0: W = in_w;               out = iw0;   break;
    case 1: W = in_w + 512 * 512;   out = iw1;   break;
    case 2: W = in_w + 2 * 512 * 512; out = iw2; break;
    case 3: W = Wo;                 out = Wo_pk; break;
    default: W = W1;                out = W1_pk; break;
  }
  pack_chunk(W, out, 512, 0, within * 256 + threadIdx.x);
}

__global__ __launch_bounds__(256) void pack2_k(const float* __restrict__ Wqp,
    const float* __restrict__ Wkp, const float* __restrict__ Wvp,
    unsigned short* Wqp_pk, unsigned short* kv_pk) {
  int bid = blockIdx.x, tid = threadIdx.x;
  if (bid < 128)      pack_chunk(Wqp, Wqp_pk, 512, 0, bid * 256 + tid);
  else if (bid < 320) pack_chunk(Wkp, kv_pk, 768, 0, (bid - 128) * 256 + tid);
  else                pack_chunk(Wvp, kv_pk, 768, 4, (bid - 320) * 256 + tid);
}

// ---------------- 64x128-tile bf16 MFMA GEMM body ----------------------------
__device__ __forceinline__ void mgemm64(const float* __restrict__ A,
    const unsigned short* __restrict__ Bpk, const float* __restrict__ bias,
    float* __restrict__ C, __bf16* __restrict__ Cb,
    int M, int N, int K, int xt, int yt,
    unsigned short* Al, unsigned short* Bl) {
  const int tid = threadIdx.x;
  const int lane = tid & 63, wid = tid >> 6;
  const int wr = wid >> 1, wc = wid & 1;
  const int row0 = yt * 64, col0 = xt * 128;
  const int KT = K >> 5;
  f32x4 acc[2][4];
#pragma unroll
  for (int m = 0; m < 2; ++m)
#pragma unroll
    for (int n = 0; n < 4; ++n) acc[m][n] = (f32x4){0.f, 0.f, 0.f, 0.f};
  const int kb0 = tid & 3, ar = tid >> 2;
  const unsigned short* bsrc = Bpk + (size_t)xt * KT * 4096;

  for (int kt = 0; kt < KT; ++kt) {
    {
      const unsigned short* g1 = bsrc + (size_t)kt * 4096 + wid * 512 + lane * 8;
      __builtin_amdgcn_global_load_lds(
          (const __attribute__((address_space(1))) void*)g1,
          (__attribute__((address_space(3))) void*)&Bl[wid * 512], 16, 0, 0);
      __builtin_amdgcn_global_load_lds(
          (const __attribute__((address_space(1))) void*)(g1 + 2048),
          (__attribute__((address_space(3))) void*)&Bl[2048 + wid * 512], 16, 0, 0);
    }
    {
      const float* ap = A + (size_t)(row0 + ar) * K + kt * 32 + kb0 * 8;
      float4 f0 = *(const float4*)ap;
      float4 f1 = *(const float4*)(ap + 4);
      int4 pk;
      pk.x = f2bf(f0.x) | (f2bf(f0.y) << 16);
      pk.y = f2bf(f0.z) | (f2bf(f0.w) << 16);
      pk.z = f2bf(f1.x) | (f2bf(f1.y) << 16);
      pk.w = f2bf(f1.z) | (f2bf(f1.w) << 16);
      *(int4*)&Al[(ar >> 4) * 512 + kb0 * 128 + (ar & 15) * 8] = pk;
    }
    __syncthreads();
    bf16x8 af[2], bfr[4];
#pragma unroll
    for (int m = 0; m < 2; ++m)
      af[m] = *(const bf16x8*)&Al[(wr * 2 + m) * 512 + lane * 8];
#pragma unroll
    for (int n = 0; n < 4; ++n)
      bfr[n] = *(const bf16x8*)&Bl[(wc * 4 + n) * 512 + lane * 8];
#pragma unroll
    for (int m = 0; m < 2; ++m)
#pragma unroll
      for (int n = 0; n < 4; ++n)
        acc[m][n] = __builtin_amdgcn_mfma_f32_16x16x32_bf16(af[m], bfr[n], acc[m][n], 0, 0, 0);
    __syncthreads();
  }
  const int cl = lane & 15, rg = lane >> 4;
  float bv[4];
#pragma unroll
  for (int n = 0; n < 4; ++n)
    bv[n] = bias ? bias[col0 + wc * 64 + n * 16 + cl] : 0.f;
#pragma unroll
  for (int m = 0; m < 2; ++m) {
    int r = row0 + wr * 32 + m * 16 + rg * 4;
#pragma unroll
    for (int n = 0; n < 4; ++n) {
      int c = col0 + wc * 64 + n * 16 + cl;
#pragma unroll
      for (int i = 0; i < 4; ++i) {
        float v = acc[m][n][i] + bv[n];
        if (Cb) Cb[(size_t)(r + i) * N + c] = (__bf16)v;
        else    C[(size_t)(r + i) * N + c] = v;
      }
    }
  }
}

__global__ __launch_bounds__(256) void gemm64_k(const float* __restrict__ A,
    const unsigned short* __restrict__ Bpk, const float* __restrict__ bias,
    float* __restrict__ C, int M, int N, int K) {
  __shared__ __align__(16) unsigned short Al[2048];
  __shared__ __align__(16) unsigned short Bl[4096];
  mgemm64(A, Bpk, bias, C, nullptr, M, N, K, blockIdx.x, blockIdx.y, Al, Bl);
}

__global__ __launch_bounds__(256) void fold_k(const float* __restrict__ Wq,
    const float* __restrict__ Wk, const float* __restrict__ Wv,
    const unsigned short* iw0, const unsigned short* iw1, const unsigned short* iw2,
    float* Wqp, float* Wkp, float* Wvp) {
  __shared__ __align__(16) unsigned short Al[2048];
  __shared__ __align__(16) unsigned short Bl[4096];
  int bid = blockIdx.x;
  if (bid < 32)       mgemm64(Wq, iw0, nullptr, Wqp, nullptr, 512, 512, 512, bid & 3, bid >> 2, Al, Bl);
  else if (bid < 80)  { int r = bid - 32; mgemm64(Wk, iw1, nullptr, Wkp, nullptr, 768, 512, 512, r & 3, r >> 2, Al, Bl); }
  else                { int r = bid - 80; mgemm64(Wv, iw2, nullptr, Wvp, nullptr, 768, 512, 512, r & 3, r >> 2, Al, Bl); }
}

__global__ __launch_bounds__(256) void proj_k(const float* __restrict__ dense,
    const float* __restrict__ cond, const unsigned short* Wqp_pk,
    const unsigned short* kv_pk, const float* __restrict__ bqp,
    const float* __restrict__ bkv, float* qh, __bf16* kvh, int BL) {
  __shared__ __align__(16) unsigned short Al[2048];
  __shared__ __align__(16) unsigned short Bl[4096];
  int bid = blockIdx.x;
  int nq = (BL >> 6) << 2;   // 992
  if (bid < nq)
    mgemm64(dense, Wqp_pk, bqp, qh, nullptr, BL, 512, 512, bid & 3, bid >> 2, Al, Bl);
  else {
    int r = bid - nq;
    mgemm64(cond, kv_pk, bkv, nullptr, kvh, B_ * S_, 1024, LAT_, r & 7, r >> 3, Al, Bl);
  }
}

__global__ void bias3_k(const float* __restrict__ bq, const float* __restrict__ bk,
    const float* __restrict__ bv, const float* __restrict__ in_w,
    const float* __restrict__ in_b, float* bqp, float* bkv) {
  int sel = blockIdx.x >> 1;
  int j = (blockIdx.x & 1) * 256 + threadIdx.x;
  const float* bin; const float* W; const float* badd; float* out;
  if (sel == 0)      { bin = bq; W = in_w;                 badd = in_b;          out = bqp; }
  else if (sel == 1) { bin = bk; W = in_w + 512 * 512;     badd = in_b + D_;     out = bkv; }
  else               { bin = bv; W = in_w + 2 * 512 * 512; badd = in_b + 2 * D_; out = bkv + 512; }
  float s = badd[j];
  for (int k = 0; k < D_; ++k) s += bin[k] * W[(size_t)k * D_ + j];
  out[j] = s;
}

// ---------------- MFMA attention: 8 waves/block, same grid -------------------
// wave w: QK s-range w*32 (2 n-tiles); PV output tile (m=w&1, dt=w>>1).
__device__ __forceinline__ float rmax16(float v) {
  v = fmaxf(v, __shfl_xor(v, 1)); v = fmaxf(v, __shfl_xor(v, 2));
  v = fmaxf(v, __shfl_xor(v, 4)); v = fmaxf(v, __shfl_xor(v, 8));
  return v;
}
__device__ __forceinline__ float rsum16(float v) {
  v += __shfl_xor(v, 1); v += __shfl_xor(v, 2);
  v += __shfl_xor(v, 4); v += __shfl_xor(v, 8);
  return v;
}

__global__ __launch_bounds__(512) void attn_k(const float* __restrict__ qh,
    const __bf16* __restrict__ kvh, const int* __restrict__ maskc,
    float* __restrict__ ctx, float* __restrict__ avout, int Lmax) {
  const int bid = blockIdx.x;
  const int b = bid & 15;
  const int l0 = (bid >> 4) * 32;
  const int tid = threadIdx.x;
  const int lane = tid & 63, w = tid >> 6;          // w in 0..7
  const int lg = lane >> 4, l15 = lane & 15;
  __shared__ __align__(16) __bf16 v_lds[256][68];   // 34816 B
  __shared__ __align__(16) __bf16 p_lds[32][260];   // 16640 B
  __shared__ float maxred[8][32];                   // 1024 B
  __shared__ float sumred[8][32];                   // 1024 B => 53504 total

  float madd[2];
#pragma unroll
  for (int n = 0; n < 2; ++n)
    madd[n] = maskc[b * S_ + w * 32 + n * 16 + l15] ? -1.0e30f : 0.f;

  float av[2][2][4];
#pragma unroll
  for (int m = 0; m < 2; ++m)
#pragma unroll
    for (int n = 0; n < 2; ++n)
#pragma unroll
      for (int i = 0; i < 4; ++i) av[m][n][i] = 0.f;

  const size_t qrow0 = (size_t)b * Lmax + l0;
  const int vrow = tid >> 1, vcol0 = (tid & 1) * 32;   // V staging: 4x16B/thread
  const int m2 = w & 1, dt = w >> 1;                   // PV tile assignment

#pragma unroll 1
  for (int h = 0; h < H_; ++h) {
    __syncthreads();   // guards v_lds + p_lds overwrite vs previous head's PV
    // ---- stage V tile [256][64] (bf16, straight 16B copies) ----
    {
      const __bf16* vp = kvh + (size_t)(b * S_ + vrow) * 1024 + 512 + h * DH_ + vcol0;
      *(bf16x8*)&v_lds[vrow][vcol0]      = *(const bf16x8*)vp;
      *(bf16x8*)&v_lds[vrow][vcol0 + 8]  = *(const bf16x8*)(vp + 8);
      *(bf16x8*)&v_lds[vrow][vcol0 + 16] = *(const bf16x8*)(vp + 16);
      *(bf16x8*)&v_lds[vrow][vcol0 + 24] = *(const bf16x8*)(vp + 24);
    }
    // ---- QK^T: wave handles s in [w*32, w*32+32) ----
    f32x4 qk[2][2];
#pragma unroll
    for (int m = 0; m < 2; ++m)
#pragma unroll
      for (int n = 0; n < 2; ++n) qk[m][n] = (f32x4){0.f, 0.f, 0.f, 0.f};
#pragma unroll
    for (int kt = 0; kt < 2; ++kt) {
      bf16x8 afr[2];
#pragma unroll
      for (int m = 0; m < 2; ++m) {
        const float* qp = qh + (qrow0 + m * 16 + l15) * D_ + h * DH_ + kt * 32 + lg * 8;
        float4 f0 = *(const float4*)qp, f1 = *(const float4*)(qp + 4);
        afr[m][0] = (__bf16)f0.x; afr[m][1] = (__bf16)f0.y;
        afr[m][2] = (__bf16)f0.z; afr[m][3] = (__bf16)f0.w;
        afr[m][4] = (__bf16)f1.x; afr[m][5] = (__bf16)f1.y;
        afr[m][6] = (__bf16)f1.z; afr[m][7] = (__bf16)f1.w;
      }
#pragma unroll
      for (int n = 0; n < 2; ++n) {
        const __bf16* kp = kvh + ((size_t)(b * S_) + w * 32 + n * 16 + l15) * 1024
                           + h * DH_ + kt * 32 + lg * 8;
        bf16x8 bfr = *(const bf16x8*)kp;
#pragma unroll
        for (int m = 0; m < 2; ++m)
          qk[m][n] = __builtin_amdgcn_mfma_f32_16x16x32_bf16(afr[m], bfr, qk[m][n], 0, 0, 0);
      }
    }
    // ---- scale + mask ----
#pragma unroll
    for (int m = 0; m < 2; ++m)
#pragma unroll
      for (int n = 0; n < 2; ++n)
#pragma unroll
        for (int i = 0; i < 4; ++i)
          qk[m][n][i] = qk[m][n][i] * 0.125f + madd[n];
    // ---- phase 1: wave max -> LDS ----
    float pm[2][4];
#pragma unroll
    for (int m = 0; m < 2; ++m)
#pragma unroll
      for (int i = 0; i < 4; ++i)
        pm[m][i] = rmax16(fmaxf(qk[m][0][i], qk[m][1][i]));
    if (l15 == 0) {
#pragma unroll
      for (int m = 0; m < 2; ++m)
#pragma unroll
        for (int i = 0; i < 4; ++i) maxred[w][m * 16 + lg * 4 + i] = pm[m][i];
    }
    __syncthreads();
    // ---- global max; exp; wave sum -> LDS ----
    float gm[2][4], ps[2][4];
#pragma unroll
    for (int m = 0; m < 2; ++m)
#pragma unroll
      for (int i = 0; i < 4; ++i) {
        int row = m * 16 + lg * 4 + i;
        float g0 = fmaxf(fmaxf(maxred[0][row], maxred[1][row]),
                         fmaxf(maxred[2][row], maxred[3][row]));
        float g1 = fmaxf(fmaxf(maxred[4][row], maxred[5][row]),
                         fmaxf(maxred[6][row], maxred[7][row]));
        gm[m][i] = fmaxf(g0, g1);
        ps[m][i] = 0.f;
      }
#pragma unroll
    for (int m = 0; m < 2; ++m)
#pragma unroll
      for (int n = 0; n < 2; ++n)
#pragma unroll
        for (int i = 0; i < 4; ++i) {
          float e = __expf(qk[m][n][i] - gm[m][i]);
          qk[m][n][i] = e;
          ps[m][i] += e;
        }
#pragma unroll
    for (int m = 0; m < 2; ++m)
#pragma unroll
      for (int i = 0; i < 4; ++i) pm[m][i] = rsum16(ps[m][i]);
    if (l15 == 0) {
#pragma unroll
      for (int m = 0; m < 2; ++m)
#pragma unroll
        for (int i = 0; i < 4; ++i) sumred[w][m * 16 + lg * 4 + i] = pm[m][i];
    }
    __syncthreads();
    // ---- normalize + av + P->LDS ----
#pragma unroll
    for (int m = 0; m < 2; ++m)
#pragma unroll
      for (int i = 0; i < 4; ++i) {
        int row = m * 16 + lg * 4 + i;
        float denom = (sumred[0][row] + sumred[1][row]) + (sumred[2][row] + sumred[3][row])
                    + (sumred[4][row] + sumred[5][row]) + (sumred[6][row] + sumred[7][row]);
        float inv = 1.f / denom;
#pragma unroll
        for (int n = 0; n < 2; ++n) {
          float p = qk[m][n][i] * inv;
          av[m][n][i] += p * 0.125f;
          p_lds[row][w * 32 + n * 16 + l15] = (__bf16)p;
        }
      }
    __syncthreads();
    // ---- PV: one 16x16 tile per wave (rows m2*16.., cols dt*16..) ----
    f32x4 pv = (f32x4){0.f, 0.f, 0.f, 0.f};
#pragma unroll
    for (int ks = 0; ks < 8; ++ks) {
      bf16x8 vb;
#pragma unroll
      for (int j = 0; j < 8; ++j) vb[j] = v_lds[ks * 32 + lg * 8 + j][dt * 16 + l15];
      bf16x8 pa = *(const bf16x8*)&p_lds[m2 * 16 + l15][ks * 32 + lg * 8];
      pv = __builtin_amdgcn_mfma_f32_16x16x32_bf16(pa, vb, pv, 0, 0, 0);
    }
#pragma unroll
    for (int i = 0; i < 4; ++i)
      ctx[(qrow0 + m2 * 16 + lg * 4 + i) * D_ + h * DH_ + dt * 16 + l15] = pv[i];
  }
  // ---- head-averaged weights ----
#pragma unroll
  for (int m = 0; m < 2; ++m)
#pragma unroll
    for (int i = 0; i < 4; ++i) {
      size_t arow = (qrow0 + m * 16 + lg * 4 + i) * S_;
#pragma unroll
      for (int n = 0; n < 2; ++n)
        avout[arow + w * 32 + n * 16 + l15] = av[m][n][i];
    }
}

// ---------------- x1 = LN(a + r) --------------------------------------------
__global__ __launch_bounds__(256) void ln_add_k(const float* __restrict__ a,
    const float* __restrict__ r, const float* __restrict__ g,
    const float* __restrict__ be, float* __restrict__ out) {
  size_t row = (size_t)blockIdx.x * D_;
  int tid = threadIdx.x;
  __shared__ float red[256];
  float v0 = a[row + tid]       + r[row + tid];
  float v1 = a[row + tid + 256] + r[row + tid + 256];
  red[tid] = v0 + v1;
  __syncthreads();
  for (int o = 128; o > 0; o >>= 1) { if (tid < o) red[tid] += red[tid + o]; __syncthreads(); }
  float mean = red[0] * (1.f / D_);
  __syncthreads();
  red[tid] = v0 * v0 + v1 * v1;
  __syncthreads();
  for (int o = 128; o > 0; o >>= 1) { if (tid < o) red[tid] += red[tid + o]; __syncthreads(); }
  float var = red[0] * (1.f / D_) - mean * mean;
  float rstd = rsqrtf(var + 1e-5f);
  out[row + tid]       = (v0 - mean) * rstd * g[tid]       + be[tid];
  out[row + tid + 256] = (v1 - mean) * rstd * g[tid + 256] + be[tid + 256];
}

// ---------------- out[i] = LN(leaky(h1)+x1) gathered to ragged rows ----------
__global__ __launch_bounds__(256) void final_k(const float* __restrict__ h1,
    const float* __restrict__ x1, const int* __restrict__ gb,
    const int* __restrict__ starts, const float* __restrict__ g,
    const float* __restrict__ be, float* __restrict__ out, int Lmax) {
  int i = blockIdx.x, tid = threadIdx.x;
  int b = gb[i], p = i - starts[b];
  size_t row = ((size_t)b * Lmax + p) * D_;
  __shared__ float red[256];
  float t0 = h1[row + tid];       t0 = (t0 >= 0.f) ? t0 : 0.01f * t0; t0 += x1[row + tid];
  float t1 = h1[row + tid + 256]; t1 = (t1 >= 0.f) ? t1 : 0.01f * t1; t1 += x1[row + tid + 256];
  red[tid] = t0 + t1;
  __syncthreads();
  for (int o = 128; o > 0; o >>= 1) { if (tid < o) red[tid] += red[tid + o]; __syncthreads(); }
  float mean = red[0] * (1.f / D_);
  __syncthreads();
  red[tid] = t0 * t0 + t1 * t1;
  __syncthreads();
  for (int o = 128; o > 0; o >>= 1) { if (tid < o) red[tid] += red[tid + o]; __syncthreads(); }
  float var = red[0] * (1.f / D_) - mean * mean;
  float rstd = rsqrtf(var + 1e-5f);
  out[(size_t)i * D_ + tid]       = (t0 - mean) * rstd * g[tid]       + be[tid];
  out[(size_t)i * D_ + tid + 256] = (t1 - mean) * rstd * g[tid + 256] + be[tid + 256];
}

// ---------------- host launcher ----------------------------------------------
extern "C" void kernel_launch(void* const* d_in, const int* in_sizes, int n_in,
                              void* d_out, int out_size, void* d_ws, size_t ws_size,
                              hipStream_t stream) {
  const float* nodes = (const float*)d_in[0];
  const int*   gb    = (const int*)d_in[1];
  const float* cond  = (const float*)d_in[2];
  const void*  maskp = d_in[3];
  const float* Wq   = (const float*)d_in[6];
  const float* bq   = (const float*)d_in[7];
  const float* Wk   = (const float*)d_in[8];
  const float* bk   = (const float*)d_in[9];
  const float* Wv   = (const float*)d_in[10];
  const float* bv   = (const float*)d_in[11];
  const float* in_w = (const float*)d_in[12];
  const float* in_b = (const float*)d_in[13];
  const float* Wo   = (const float*)d_in[14];
  const float* bo   = (const float*)d_in[15];
  const float* g1   = (const float*)d_in[16];
  const float* b1ln = (const float*)d_in[17];
  const float* W1   = (const float*)d_in[18];
  const float* b1f  = (const float*)d_in[19];
  const float* g2   = (const float*)d_in[20];
  const float* b2ln = (const float*)d_in[21];

  const int N    = in_sizes[0] / D_;                    // 12032
  const int Lmax = (out_size - N * D_) / (B_ * S_);     // 992
  const int BL   = B_ * Lmax;                           // 15872

  float* ws = (float*)d_ws;
  int* starts = (int*)(ws + 0);
  int* maskc  = (int*)(ws + 64);
  size_t o = 8192;
  float* dense = ws + o; o += (size_t)BL * D_;
  float* qh    = ws + o; o += (size_t)BL * D_;
  float* ctx   = qh;              // alias safe: head-h Q read before head-h ctx write, same rows
  __bf16* kvh  = (__bf16*)(ws + o); o += (size_t)B_ * S_ * 1024 / 2;  // bf16 [4096][1024]
  float* tmp   = ws + o; o += (size_t)BL * D_;
  float* x1    = ws + o; o += (size_t)BL * D_;
  float* h1    = dense;           // alias: dense dead after ln_add_k
  float* Wqp = ws + o; o += (size_t)D_ * D_;
  float* Wkp = ws + o; o += (size_t)LAT_ * D_;
  float* Wvp = ws + o; o += (size_t)LAT_ * D_;
  float* bqp = ws + o; o += D_;
  float* bkv = ws + o; o += 1024;
  unsigned short* iw0_pk = (unsigned short*)(ws + o); o += (size_t)D_ * D_ / 2;
  unsigned short* iw1_pk = (unsigned short*)(ws + o); o += (size_t)D_ * D_ / 2;
  unsigned short* iw2_pk = (unsigned short*)(ws + o); o += (size_t)D_ * D_ / 2;
  unsigned short* Wqp_pk = (unsigned short*)(ws + o); o += (size_t)D_ * D_ / 2;
  unsigned short* kv_pk  = (unsigned short*)(ws + o); o += (size_t)LAT_ * 1024 / 2;
  unsigned short* Wo_pk  = (unsigned short*)(ws + o); o += (size_t)D_ * D_ / 2;
  unsigned short* W1_pk  = (unsigned short*)(ws + o); o += (size_t)D_ * D_ / 2;

  (void)hipMemsetAsync(d_ws, 0, (8192 + (size_t)BL * D_) * sizeof(float), stream);

  prep_k<<<(N + 255) / 256, 256, 0, stream>>>(maskp, maskc, gb, starts, N);
  scatter_k<<<N, 256, 0, stream>>>(nodes, gb, starts, dense, Lmax);

  pack1_k<<<640, 256, 0, stream>>>(in_w, Wo, W1, iw0_pk, iw1_pk, iw2_pk, Wo_pk, W1_pk);
  fold_k<<<128, 256, 0, stream>>>(Wq, Wk, Wv, iw0_pk, iw1_pk, iw2_pk, Wqp, Wkp, Wvp);
  pack2_k<<<512, 256, 0, stream>>>(Wqp, Wkp, Wvp, Wqp_pk, kv_pk);
  bias3_k<<<6, 256, 0, stream>>>(bq, bk, bv, in_w, in_b, bqp, bkv);

  proj_k<<<(BL >> 6) * 4 + 512, 256, 0, stream>>>(dense, cond, Wqp_pk, kv_pk,
      bqp, bkv, qh, kvh, BL);

  attn_k<<<(Lmax / 32) * B_, 512, 0, stream>>>(qh, kvh, maskc, ctx,
      (float*)d_out + (size_t)N * D_, Lmax);

  gemm64_k<<<dim3(4, BL / 64), 256, 0, stream>>>(ctx, Wo_pk, bo, tmp, BL, D_, D_);
  ln_add_k<<<BL, 256, 0, stream>>>(tmp, dense, g1, b1ln, x1);

  gemm64_k<<<dim3(4, BL / 64), 256, 0, stream>>>(x1, W1_pk, b1f, h1, BL, D_, D_);
  final_k<<<N, 256, 0, stream>>>(h1, x1, gb, starts, g2, b2ln, (float*)d_out, Lmax);
}

// Round 13
// 247.354 us; speedup vs baseline: 1.1047x; 1.1047x over previous
//
#include <hip/hip_runtime.h>
#include <math.h>

#define D_   512
#define LAT_ 768
#define B_   16
#define S_   256
#define H_   8
#define DH_  64

typedef __bf16 bf16x8 __attribute__((ext_vector_type(8)));
typedef float f32x4 __attribute__((ext_vector_type(4)));

__device__ __forceinline__ unsigned short f2bf(float f) {
  unsigned u = __float_as_uint(f);
  unsigned r = (u + 0x7fffu + ((u >> 16) & 1u)) >> 16;
  return (unsigned short)r;
}

// ---------------- fused prep: mask canonicalization + segment starts ---------
__global__ void prep_k(const void* __restrict__ mask, int* __restrict__ maskc,
                       const int* __restrict__ gb, int* __restrict__ starts, int n) {
  int i = blockIdx.x * blockDim.x + threadIdx.x;
  if (i < B_ * S_) {
    const unsigned char* pb = (const unsigned char*)mask;
    const int*   pi = (const int*)mask;
    const float* pf = (const float*)mask;
    unsigned int w = ((const unsigned int*)mask)[1023];
    int v;
    if (w == 0x01010101u)      v = pb[i];
    else if (w == 0x3f800000u) v = (pf[i] != 0.0f);
    else                       v = (pi[i] != 0);
    maskc[i] = v ? 1 : 0;
  }
  if (i < n) {
    if (i == 0 || gb[i] != gb[i - 1]) starts[gb[i]] = i;
  }
}

// ---------------- scatter ragged nodes -> dense [B,Lmax,D] -------------------
__global__ __launch_bounds__(256) void scatter_k(const float* __restrict__ nodes,
    const int* __restrict__ gb, const int* __restrict__ starts,
    float* __restrict__ dense, int Lmax) {
  int i = blockIdx.x;
  int b = gb[i], p = i - starts[b];
  const float* src = nodes + (size_t)i * D_;
  float* dst = dense + ((size_t)b * Lmax + p) * D_;
  dst[threadIdx.x]       = src[threadIdx.x];
  dst[threadIdx.x + 256] = src[threadIdx.x + 256];
}

// ---------------- pack one (kc,n) chunk of B into MFMA layout ----------------
__device__ __forceinline__ void pack_chunk(const float* __restrict__ W,
    unsigned short* __restrict__ out, int K, int ntoff, int idx) {
  int n = idx & 511, kc = idx >> 9;
  int kt = kc >> 2, kblk = kc & 3;
  int nt = n >> 7, nblk = (n >> 4) & 7, col = n & 15;
  int KT = K >> 5;
  size_t ob = ((size_t)((nt + ntoff) * KT + kt) * 4096) + nblk * 512 + kblk * 128 + col * 8;
  unsigned short v[8];
#pragma unroll
  for (int j = 0; j < 8; ++j) v[j] = f2bf(W[(size_t)(kc * 8 + j) * 512 + n]);
  int4 pk;
  pk.x = v[0] | (v[1] << 16); pk.y = v[2] | (v[3] << 16);
  pk.z = v[4] | (v[5] << 16); pk.w = v[6] | (v[7] << 16);
  *(int4*)&out[ob] = pk;
}

__global__ __launch_bounds__(256) void pack1_k(const float* __restrict__ in_w,
    const float* __restrict__ Wo, const float* __restrict__ W1,
    unsigned short* iw0, unsigned short* iw1, unsigned short* iw2,
    unsigned short* Wo_pk, unsigned short* W1_pk) {
  int bid = blockIdx.x, sel = bid >> 7, within = bid & 127;
  const float* W; unsigned short* out;
  switch (sel) {
    case 0: W = in_w;               out = iw0;   break;
    case 1: W = in_w + 512 * 512;   out = iw1;   break;
    case 2: W = in_w + 2 * 512 * 512; out = iw2; break;
    case 3: W = Wo;                 out = Wo_pk; break;
    default: W = W1;                out = W1_pk; break;
  }
  pack_chunk(W, out, 512, 0, within * 256 + threadIdx.x);
}

__global__ __launch_bounds__(256) void pack2_k(const float* __restrict__ Wqp,
    const float* __restrict__ Wkp, const float* __restrict__ Wvp,
    unsigned short* Wqp_pk, unsigned short* kv_pk) {
  int bid = blockIdx.x, tid = threadIdx.x;
  if (bid < 128)      pack_chunk(Wqp, Wqp_pk, 512, 0, bid * 256 + tid);
  else if (bid < 320) pack_chunk(Wkp, kv_pk, 768, 0, (bid - 128) * 256 + tid);
  else                pack_chunk(Wvp, kv_pk, 768, 4, (bid - 320) * 256 + tid);
}

// ---------------- 64x128-tile bf16 MFMA GEMM body ----------------------------
__device__ __forceinline__ void mgemm64(const float* __restrict__ A,
    const unsigned short* __restrict__ Bpk, const float* __restrict__ bias,
    float* __restrict__ C, __bf16* __restrict__ Cb,
    int M, int N, int K, int xt, int yt,
    unsigned short* Al, unsigned short* Bl) {
  const int tid = threadIdx.x;
  const int lane = tid & 63, wid = tid >> 6;
  const int wr = wid >> 1, wc = wid & 1;
  const int row0 = yt * 64, col0 = xt * 128;
  const int KT = K >> 5;
  f32x4 acc[2][4];
#pragma unroll
  for (int m = 0; m < 2; ++m)
#pragma unroll
    for (int n = 0; n < 4; ++n) acc[m][n] = (f32x4){0.f, 0.f, 0.f, 0.f};
  const int kb0 = tid & 3, ar = tid >> 2;
  const unsigned short* bsrc = Bpk + (size_t)xt * KT * 4096;

  for (int kt = 0; kt < KT; ++kt) {
    {
      const unsigned short* g1 = bsrc + (size_t)kt * 4096 + wid * 512 + lane * 8;
      __builtin_amdgcn_global_load_lds(
          (const __attribute__((address_space(1))) void*)g1,
          (__attribute__((address_space(3))) void*)&Bl[wid * 512], 16, 0, 0);
      __builtin_amdgcn_global_load_lds(
          (const __attribute__((address_space(1))) void*)(g1 + 2048),
          (__attribute__((address_space(3))) void*)&Bl[2048 + wid * 512], 16, 0, 0);
    }
    {
      const float* ap = A + (size_t)(row0 + ar) * K + kt * 32 + kb0 * 8;
      float4 f0 = *(const float4*)ap;
      float4 f1 = *(const float4*)(ap + 4);
      int4 pk;
      pk.x = f2bf(f0.x) | (f2bf(f0.y) << 16);
      pk.y = f2bf(f0.z) | (f2bf(f0.w) << 16);
      pk.z = f2bf(f1.x) | (f2bf(f1.y) << 16);
      pk.w = f2bf(f1.z) | (f2bf(f1.w) << 16);
      *(int4*)&Al[(ar >> 4) * 512 + kb0 * 128 + (ar & 15) * 8] = pk;
    }
    __syncthreads();
    bf16x8 af[2], bfr[4];
#pragma unroll
    for (int m = 0; m < 2; ++m)
      af[m] = *(const bf16x8*)&Al[(wr * 2 + m) * 512 + lane * 8];
#pragma unroll
    for (int n = 0; n < 4; ++n)
      bfr[n] = *(const bf16x8*)&Bl[(wc * 4 + n) * 512 + lane * 8];
#pragma unroll
    for (int m = 0; m < 2; ++m)
#pragma unroll
      for (int n = 0; n < 4; ++n)
        acc[m][n] = __builtin_amdgcn_mfma_f32_16x16x32_bf16(af[m], bfr[n], acc[m][n], 0, 0, 0);
    __syncthreads();
  }
  const int cl = lane & 15, rg = lane >> 4;
  float bv[4];
#pragma unroll
  for (int n = 0; n < 4; ++n)
    bv[n] = bias ? bias[col0 + wc * 64 + n * 16 + cl] : 0.f;
#pragma unroll
  for (int m = 0; m < 2; ++m) {
    int r = row0 + wr * 32 + m * 16 + rg * 4;
#pragma unroll
    for (int n = 0; n < 4; ++n) {
      int c = col0 + wc * 64 + n * 16 + cl;
#pragma unroll
      for (int i = 0; i < 4; ++i) {
        float v = acc[m][n][i] + bv[n];
        if (Cb) Cb[(size_t)(r + i) * N + c] = (__bf16)v;
        else    C[(size_t)(r + i) * N + c] = v;
      }
    }
  }
}

__global__ __launch_bounds__(256) void gemm64_k(const float* __restrict__ A,
    const unsigned short* __restrict__ Bpk, const float* __restrict__ bias,
    float* __restrict__ C, int M, int N, int K) {
  __shared__ __align__(16) unsigned short Al[2048];
  __shared__ __align__(16) unsigned short Bl[4096];
  mgemm64(A, Bpk, bias, C, nullptr, M, N, K, blockIdx.x, blockIdx.y, Al, Bl);
}

__global__ __launch_bounds__(256) void fold_k(const float* __restrict__ Wq,
    const float* __restrict__ Wk, const float* __restrict__ Wv,
    const unsigned short* iw0, const unsigned short* iw1, const unsigned short* iw2,
    float* Wqp, float* Wkp, float* Wvp) {
  __shared__ __align__(16) unsigned short Al[2048];
  __shared__ __align__(16) unsigned short Bl[4096];
  int bid = blockIdx.x;
  if (bid < 32)       mgemm64(Wq, iw0, nullptr, Wqp, nullptr, 512, 512, 512, bid & 3, bid >> 2, Al, Bl);
  else if (bid < 80)  { int r = bid - 32; mgemm64(Wk, iw1, nullptr, Wkp, nullptr, 768, 512, 512, r & 3, r >> 2, Al, Bl); }
  else                { int r = bid - 80; mgemm64(Wv, iw2, nullptr, Wvp, nullptr, 768, 512, 512, r & 3, r >> 2, Al, Bl); }
}

__global__ __launch_bounds__(256) void proj_k(const float* __restrict__ dense,
    const float* __restrict__ cond, const unsigned short* Wqp_pk,
    const unsigned short* kv_pk, const float* __restrict__ bqp,
    const float* __restrict__ bkv, float* qh, __bf16* kvh, int BL) {
  __shared__ __align__(16) unsigned short Al[2048];
  __shared__ __align__(16) unsigned short Bl[4096];
  int bid = blockIdx.x;
  int nq = (BL >> 6) << 2;   // 992
  if (bid < nq)
    mgemm64(dense, Wqp_pk, bqp, qh, nullptr, BL, 512, 512, bid & 3, bid >> 2, Al, Bl);
  else {
    int r = bid - nq;
    mgemm64(cond, kv_pk, bkv, nullptr, kvh, B_ * S_, 1024, LAT_, r & 7, r >> 3, Al, Bl);
  }
}

__global__ void bias3_k(const float* __restrict__ bq, const float* __restrict__ bk,
    const float* __restrict__ bv, const float* __restrict__ in_w,
    const float* __restrict__ in_b, float* bqp, float* bkv) {
  int sel = blockIdx.x >> 1;
  int j = (blockIdx.x & 1) * 256 + threadIdx.x;
  const float* bin; const float* W; const float* badd; float* out;
  if (sel == 0)      { bin = bq; W = in_w;                 badd = in_b;          out = bqp; }
  else if (sel == 1) { bin = bk; W = in_w + 512 * 512;     badd = in_b + D_;     out = bkv; }
  else               { bin = bv; W = in_w + 2 * 512 * 512; badd = in_b + 2 * D_; out = bkv + 512; }
  float s = badd[j];
  for (int k = 0; k < D_; ++k) s += bin[k] * W[(size_t)k * D_ + j];
  out[j] = s;
}

// ---------------- MFMA attention: R10 softmax + R11 padding diet -------------
__device__ __forceinline__ float rmax16(float v) {
  v = fmaxf(v, __shfl_xor(v, 1)); v = fmaxf(v, __shfl_xor(v, 2));
  v = fmaxf(v, __shfl_xor(v, 4)); v = fmaxf(v, __shfl_xor(v, 8));
  return v;
}
__device__ __forceinline__ float rsum16(float v) {
  v += __shfl_xor(v, 1); v += __shfl_xor(v, 2);
  v += __shfl_xor(v, 4); v += __shfl_xor(v, 8);
  return v;
}

__global__ __launch_bounds__(256) void attn_k(const float* __restrict__ qh,
    const __bf16* __restrict__ kvh, const int* __restrict__ maskc,
    float* __restrict__ ctx, float* __restrict__ avout, int Lmax) {
  const int bid = blockIdx.x;
  const int b = bid & 15;
  const int l0 = (bid >> 4) * 32;
  const int tid = threadIdx.x;
  const int lane = tid & 63, w = tid >> 6;
  const int lg = lane >> 4, l15 = lane & 15;
  __shared__ __align__(16) __bf16 v_lds[256][68];
  __shared__ __align__(16) __bf16 p_lds[32][260];
  __shared__ float maxred[4][32];
  __shared__ float sumred[4][32];
  float madd[4];
#pragma unroll
  for (int n = 0; n < 4; ++n)
    madd[n] = maskc[b * S_ + w * 64 + n * 16 + l15] ? -1.0e30f : 0.f;

  float av[2][4][4];
#pragma unroll
  for (int m = 0; m < 2; ++m)
#pragma unroll
    for (int n = 0; n < 4; ++n)
#pragma unroll
      for (int i = 0; i < 4; ++i) av[m][n][i] = 0.f;

  const size_t qrow0 = (size_t)b * Lmax + l0;
  const int srow = tid >> 2, scol = (tid & 3) * 16;

#pragma unroll 1
  for (int h = 0; h < H_; ++h) {
    __syncthreads();   // guards v_lds + p_lds overwrite vs previous head's PV
#pragma unroll
    for (int pass = 0; pass < 4; ++pass) {
      int s = pass * 64 + srow;
      const __bf16* vp = kvh + (size_t)(b * S_ + s) * 1024 + 512 + h * DH_ + scol;
      *(bf16x8*)&v_lds[s][scol]     = *(const bf16x8*)vp;
      *(bf16x8*)&v_lds[s][scol + 8] = *(const bf16x8*)(vp + 8);
    }
    f32x4 qk[2][4];
#pragma unroll
    for (int m = 0; m < 2; ++m)
#pragma unroll
      for (int n = 0; n < 4; ++n) qk[m][n] = (f32x4){0.f, 0.f, 0.f, 0.f};
#pragma unroll
    for (int kt = 0; kt < 2; ++kt) {
      bf16x8 afr[2];
#pragma unroll
      for (int m = 0; m < 2; ++m) {
        const float* qp = qh + (qrow0 + m * 16 + l15) * D_ + h * DH_ + kt * 32 + lg * 8;
        float4 f0 = *(const float4*)qp, f1 = *(const float4*)(qp + 4);
        afr[m][0] = (__bf16)f0.x; afr[m][1] = (__bf16)f0.y;
        afr[m][2] = (__bf16)f0.z; afr[m][3] = (__bf16)f0.w;
        afr[m][4] = (__bf16)f1.x; afr[m][5] = (__bf16)f1.y;
        afr[m][6] = (__bf16)f1.z; afr[m][7] = (__bf16)f1.w;
      }
#pragma unroll
      for (int n = 0; n < 4; ++n) {
        const __bf16* kp = kvh + ((size_t)(b * S_) + w * 64 + n * 16 + l15) * 1024
                           + h * DH_ + kt * 32 + lg * 8;
        bf16x8 bfr = *(const bf16x8*)kp;
#pragma unroll
        for (int m = 0; m < 2; ++m)
          qk[m][n] = __builtin_amdgcn_mfma_f32_16x16x32_bf16(afr[m], bfr, qk[m][n], 0, 0, 0);
      }
    }
#pragma unroll
    for (int m = 0; m < 2; ++m)
#pragma unroll
      for (int n = 0; n < 4; ++n)
#pragma unroll
        for (int i = 0; i < 4; ++i)
          qk[m][n][i] = qk[m][n][i] * 0.125f + madd[n];
    // ---- phase 1: wave max ----
    float pm[2][4];
#pragma unroll
    for (int m = 0; m < 2; ++m)
#pragma unroll
      for (int i = 0; i < 4; ++i) {
        float v = fmaxf(fmaxf(qk[m][0][i], qk[m][1][i]), fmaxf(qk[m][2][i], qk[m][3][i]));
        pm[m][i] = rmax16(v);
      }
    if (l15 == 0) {
#pragma unroll
      for (int m = 0; m < 2; ++m)
#pragma unroll
        for (int i = 0; i < 4; ++i) maxred[w][m * 16 + lg * 4 + i] = pm[m][i];
    }
    __syncthreads();
    // ---- global max; exp; wave sum ----
    float gm[2][4], ps[2][4];
#pragma unroll
    for (int m = 0; m < 2; ++m)
#pragma unroll
      for (int i = 0; i < 4; ++i) {
        int row = m * 16 + lg * 4 + i;
        gm[m][i] = fmaxf(fmaxf(maxred[0][row], maxred[1][row]),
                         fmaxf(maxred[2][row], maxred[3][row]));
        ps[m][i] = 0.f;
      }
#pragma unroll
    for (int m = 0; m < 2; ++m)
#pragma unroll
      for (int n = 0; n < 4; ++n)
#pragma unroll
        for (int i = 0; i < 4; ++i) {
          float e = __expf(qk[m][n][i] - gm[m][i]);
          qk[m][n][i] = e;
          ps[m][i] += e;
        }
#pragma unroll
    for (int m = 0; m < 2; ++m)
#pragma unroll
      for (int i = 0; i < 4; ++i) pm[m][i] = rsum16(ps[m][i]);
    if (l15 == 0) {
#pragma unroll
      for (int m = 0; m < 2; ++m)
#pragma unroll
        for (int i = 0; i < 4; ++i) sumred[w][m * 16 + lg * 4 + i] = pm[m][i];
    }
    __syncthreads();
    // ---- normalize + av + P->LDS ----
#pragma unroll
    for (int m = 0; m < 2; ++m)
#pragma unroll
      for (int i = 0; i < 4; ++i) {
        int row = m * 16 + lg * 4 + i;
        float inv = 1.f / (sumred[0][row] + sumred[1][row] + sumred[2][row] + sumred[3][row]);
#pragma unroll
        for (int n = 0; n < 4; ++n) {
          float p = qk[m][n][i] * inv;
          av[m][n][i] += p * 0.125f;
          p_lds[row][w * 64 + n * 16 + l15] = (__bf16)p;
        }
      }
    __syncthreads();
    // ---- PV ----
    f32x4 pv[2];
    pv[0] = (f32x4){0.f, 0.f, 0.f, 0.f};
    pv[1] = (f32x4){0.f, 0.f, 0.f, 0.f};
#pragma unroll
    for (int ks = 0; ks < 8; ++ks) {
      bf16x8 vb;
#pragma unroll
      for (int j = 0; j < 8; ++j) vb[j] = v_lds[ks * 32 + lg * 8 + j][w * 16 + l15];
#pragma unroll
      for (int m = 0; m < 2; ++m) {
        bf16x8 pa = *(const bf16x8*)&p_lds[m * 16 + l15][ks * 32 + lg * 8];
        pv[m] = __builtin_amdgcn_mfma_f32_16x16x32_bf16(pa, vb, pv[m], 0, 0, 0);
      }
    }
#pragma unroll
    for (int m = 0; m < 2; ++m)
#pragma unroll
      for (int i = 0; i < 4; ++i)
        ctx[(qrow0 + m * 16 + lg * 4 + i) * D_ + h * DH_ + w * 16 + l15] = pv[m][i];
  }
#pragma unroll
  for (int m = 0; m < 2; ++m)
#pragma unroll
    for (int i = 0; i < 4; ++i) {
      size_t arow = (qrow0 + m * 16 + lg * 4 + i) * S_;
#pragma unroll
      for (int n = 0; n < 4; ++n)
        avout[arow + w * 64 + n * 16 + l15] = av[m][n][i];
    }
}

// ---------------- x1 = LN(a + r): wave-per-row, no barriers ------------------
__global__ __launch_bounds__(256) void ln_add_k(const float* __restrict__ a,
    const float* __restrict__ r, const float* __restrict__ g,
    const float* __restrict__ be, float* __restrict__ out) {
  const int wv = threadIdx.x >> 6, lane = threadIdx.x & 63;
  const size_t row = ((size_t)blockIdx.x * 4 + wv) * D_;
  const int c0 = lane * 8;
  float4 a0 = *(const float4*)(a + row + c0);
  float4 a1 = *(const float4*)(a + row + c0 + 4);
  float4 r0 = *(const float4*)(r + row + c0);
  float4 r1 = *(const float4*)(r + row + c0 + 4);
  float v[8] = {a0.x + r0.x, a0.y + r0.y, a0.z + r0.z, a0.w + r0.w,
                a1.x + r1.x, a1.y + r1.y, a1.z + r1.z, a1.w + r1.w};
  float s = 0.f, sq = 0.f;
#pragma unroll
  for (int j = 0; j < 8; ++j) { s += v[j]; sq += v[j] * v[j]; }
#pragma unroll
  for (int off = 1; off < 64; off <<= 1) {
    s  += __shfl_xor(s, off);
    sq += __shfl_xor(sq, off);
  }
  float mean = s * (1.f / D_);
  float var  = sq * (1.f / D_) - mean * mean;
  float rstd = rsqrtf(var + 1e-5f);
  float4 o0, o1;
  o0.x = (v[0] - mean) * rstd * g[c0 + 0] + be[c0 + 0];
  o0.y = (v[1] - mean) * rstd * g[c0 + 1] + be[c0 + 1];
  o0.z = (v[2] - mean) * rstd * g[c0 + 2] + be[c0 + 2];
  o0.w = (v[3] - mean) * rstd * g[c0 + 3] + be[c0 + 3];
  o1.x = (v[4] - mean) * rstd * g[c0 + 4] + be[c0 + 4];
  o1.y = (v[5] - mean) * rstd * g[c0 + 5] + be[c0 + 5];
  o1.z = (v[6] - mean) * rstd * g[c0 + 6] + be[c0 + 6];
  o1.w = (v[7] - mean) * rstd * g[c0 + 7] + be[c0 + 7];
  *(float4*)(out + row + c0)     = o0;
  *(float4*)(out + row + c0 + 4) = o1;
}

// ---------------- out[i] = LN(leaky(h1)+x1), wave-per-node-row ---------------
__global__ __launch_bounds__(256) void final_k(const float* __restrict__ h1,
    const float* __restrict__ x1, const int* __restrict__ gb,
    const int* __restrict__ starts, const float* __restrict__ g,
    const float* __restrict__ be, float* __restrict__ out, int Lmax) {
  const int wv = threadIdx.x >> 6, lane = threadIdx.x & 63;
  const int i = blockIdx.x * 4 + wv;
  const int b = gb[i], p = i - starts[b];
  const size_t row = ((size_t)b * Lmax + p) * D_;
  const int c0 = lane * 8;
  float4 h0 = *(const float4*)(h1 + row + c0);
  float4 h4 = *(const float4*)(h1 + row + c0 + 4);
  float4 x0 = *(const float4*)(x1 + row + c0);
  float4 x4 = *(const float4*)(x1 + row + c0 + 4);
  float v[8] = {h0.x, h0.y, h0.z, h0.w, h4.x, h4.y, h4.z, h4.w};
  float xr[8] = {x0.x, x0.y, x0.z, x0.w, x4.x, x4.y, x4.z, x4.w};
  float s = 0.f, sq = 0.f;
#pragma unroll
  for (int j = 0; j < 8; ++j) {
    float t = v[j];
    t = (t >= 0.f) ? t : 0.01f * t;
    t += xr[j];
    v[j] = t;
    s += t; sq += t * t;
  }
#pragma unroll
  for (int off = 1; off < 64; off <<= 1) {
    s  += __shfl_xor(s, off);
    sq += __shfl_xor(sq, off);
  }
  float mean = s * (1.f / D_);
  float var  = sq * (1.f / D_) - mean * mean;
  float rstd = rsqrtf(var + 1e-5f);
  float4 o0, o1;
  o0.x = (v[0] - mean) * rstd * g[c0 + 0] + be[c0 + 0];
  o0.y = (v[1] - mean) * rstd * g[c0 + 1] + be[c0 + 1];
  o0.z = (v[2] - mean) * rstd * g[c0 + 2] + be[c0 + 2];
  o0.w = (v[3] - mean) * rstd * g[c0 + 3] + be[c0 + 3];
  o1.x = (v[4] - mean) * rstd * g[c0 + 4] + be[c0 + 4];
  o1.y = (v[5] - mean) * rstd * g[c0 + 5] + be[c0 + 5];
  o1.z = (v[6] - mean) * rstd * g[c0 + 6] + be[c0 + 6];
  o1.w = (v[7] - mean) * rstd * g[c0 + 7] + be[c0 + 7];
  *(float4*)(out + (size_t)i * D_ + c0)     = o0;
  *(float4*)(out + (size_t)i * D_ + c0 + 4) = o1;
}

// ---------------- host launcher ----------------------------------------------
extern "C" void kernel_launch(void* const* d_in, const int* in_sizes, int n_in,
                              void* d_out, int out_size, void* d_ws, size_t ws_size,
                              hipStream_t stream) {
  const float* nodes = (const float*)d_in[0];
  const int*   gb    = (const int*)d_in[1];
  const float* cond  = (const float*)d_in[2];
  const void*  maskp = d_in[3];
  const float* Wq   = (const float*)d_in[6];
  const float* bq   = (const float*)d_in[7];
  const float* Wk   = (const float*)d_in[8];
  const float* bk   = (const float*)d_in[9];
  const float* Wv   = (const float*)d_in[10];
  const float* bv   = (const float*)d_in[11];
  const float* in_w = (const float*)d_in[12];
  const float* in_b = (const float*)d_in[13];
  const float* Wo   = (const float*)d_in[14];
  const float* bo   = (const float*)d_in[15];
  const float* g1   = (const float*)d_in[16];
  const float* b1ln = (const float*)d_in[17];
  const float* W1   = (const float*)d_in[18];
  const float* b1f  = (const float*)d_in[19];
  const float* g2   = (const float*)d_in[20];
  const float* b2ln = (const float*)d_in[21];

  const int N    = in_sizes[0] / D_;                    // 12032
  const int Lmax = (out_size - N * D_) / (B_ * S_);     // 992
  const int BL   = B_ * Lmax;                           // 15872

  float* ws = (float*)d_ws;
  int* starts = (int*)(ws + 0);
  int* maskc  = (int*)(ws + 64);
  size_t o = 8192;
  float* dense = ws + o; o += (size_t)BL * D_;
  float* qh    = ws + o; o += (size_t)BL * D_;
  float* ctx   = qh;              // alias safe: head-h Q read before head-h ctx write, same rows
  __bf16* kvh  = (__bf16*)(ws + o); o += (size_t)B_ * S_ * 1024 / 2;  // bf16 [4096][1024]
  float* tmp   = ws + o; o += (size_t)BL * D_;
  float* x1    = ws + o; o += (size_t)BL * D_;
  float* h1    = dense;           // alias: dense dead after ln_add_k
  float* Wqp = ws + o; o += (size_t)D_ * D_;
  float* Wkp = ws + o; o += (size_t)LAT_ * D_;
  float* Wvp = ws + o; o += (size_t)LAT_ * D_;
  float* bqp = ws + o; o += D_;
  float* bkv = ws + o; o += 1024;
  unsigned short* iw0_pk = (unsigned short*)(ws + o); o += (size_t)D_ * D_ / 2;
  unsigned short* iw1_pk = (unsigned short*)(ws + o); o += (size_t)D_ * D_ / 2;
  unsigned short* iw2_pk = (unsigned short*)(ws + o); o += (size_t)D_ * D_ / 2;
  unsigned short* Wqp_pk = (unsigned short*)(ws + o); o += (size_t)D_ * D_ / 2;
  unsigned short* kv_pk  = (unsigned short*)(ws + o); o += (size_t)LAT_ * 1024 / 2;
  unsigned short* Wo_pk  = (unsigned short*)(ws + o); o += (size_t)D_ * D_ / 2;
  unsigned short* W1_pk  = (unsigned short*)(ws + o); o += (size_t)D_ * D_ / 2;

  (void)hipMemsetAsync(d_ws, 0, (8192 + (size_t)BL * D_) * sizeof(float), stream);

  prep_k<<<(N + 255) / 256, 256, 0, stream>>>(maskp, maskc, gb, starts, N);
  scatter_k<<<N, 256, 0, stream>>>(nodes, gb, starts, dense, Lmax);

  pack1_k<<<640, 256, 0, stream>>>(in_w, Wo, W1, iw0_pk, iw1_pk, iw2_pk, Wo_pk, W1_pk);
  fold_k<<<128, 256, 0, stream>>>(Wq, Wk, Wv, iw0_pk, iw1_pk, iw2_pk, Wqp, Wkp, Wvp);
  pack2_k<<<512, 256, 0, stream>>>(Wqp, Wkp, Wvp, Wqp_pk, kv_pk);
  bias3_k<<<6, 256, 0, stream>>>(bq, bk, bv, in_w, in_b, bqp, bkv);

  proj_k<<<(BL >> 6) * 4 + 512, 256, 0, stream>>>(dense, cond, Wqp_pk, kv_pk,
      bqp, bkv, qh, kvh, BL);

  attn_k<<<(Lmax / 32) * B_, 256, 0, stream>>>(qh, kvh, maskc, ctx,
      (float*)d_out + (size_t)N * D_, Lmax);

  gemm64_k<<<dim3(4, BL / 64), 256, 0, stream>>>(ctx, Wo_pk, bo, tmp, BL, D_, D_);
  ln_add_k<<<BL / 4, 256, 0, stream>>>(tmp, dense, g1, b1ln, x1);

  gemm64_k<<<dim3(4, BL / 64), 256, 0, stream>>>(x1, W1_pk, b1f, h1, BL, D_, D_);
  final_k<<<N / 4, 256, 0, stream>>>(h1, x1, gb, starts, g2, b2ln, (float*)d_out, Lmax);
}